// Round 1
// baseline (105.469 us; speedup 1.0000x reference)
//
#include <hip/hip_runtime.h>

#define IMG_H 1080
#define IMG_W 1920
#define NPIX (IMG_H * IMG_W)
#define NMIP 8
#define NCH 3
#define MH 128
#define MW 256
#define MIN_R 0.08f
#define MAX_R 0.5f

__global__ __launch_bounds__(256) void envlight_kernel(
    const float* __restrict__ x,      // (H,W,3)
    const float* __restrict__ rough,  // (H,W,1)
    const float* __restrict__ mips,   // (8,3,128,256)
    float* __restrict__ out)          // (H,W,3)
{
    int pix = blockIdx.x * blockDim.x + threadIdx.x;
    if (pix >= NPIX) return;

    float dx = x[pix * 3 + 0];
    float dy = x[pix * 3 + 1];
    float dz = x[pix * 3 + 2];

    // dir -> equirect uv -> grid coords in [-1,1]
    const float INV_PI = 0.31830988618379067f;
    float theta = acosf(fminf(fmaxf(dz, -1.0f), 1.0f));
    float phi = atan2f(dy, dx);
    float gx = phi * INV_PI;                  // 2u-1 = phi/pi
    float gy = 2.0f * theta * INV_PI - 1.0f;  // 2v-1 = 2*theta/pi - 1

    // grid_sample unnormalized coords (align_corners=False)
    float ix = ((gx + 1.0f) * (float)MW - 1.0f) * 0.5f;
    float iy = ((gy + 1.0f) * (float)MH - 1.0f) * 0.5f;
    float x0f = floorf(ix);
    float y0f = floorf(iy);
    float wx = ix - x0f;
    float wy = iy - y0f;
    int x0 = (int)x0f;
    int y0 = (int)y0f;
    int x0i = min(max(x0, 0), MW - 1);
    int x1i = min(max(x0 + 1, 0), MW - 1);   // border padding = clamp
    int y0i = min(max(y0, 0), MH - 1);
    int y1i = min(max(y0 + 1, 0), MH - 1);

    // roughness -> fractional mip index
    float r = fminf(fmaxf(rough[pix], MIN_R), MAX_R);
    float idx = (r - MIN_R) * ((float)(NMIP - 1) / (MAX_R - MIN_R));
    float idxf = floorf(idx);
    int i0 = min(max((int)idxf, 0), NMIP - 2);
    int i1 = min(max((int)ceilf(idx), 0), NMIP - 1);
    float w = idx - idxf;

    float w00 = (1.0f - wx) * (1.0f - wy);
    float w01 = wx * (1.0f - wy);
    float w10 = (1.0f - wx) * wy;
    float w11 = wx * wy;

    int o00 = y0i * MW + x0i;
    int o01 = y0i * MW + x1i;
    int o10 = y1i * MW + x0i;
    int o11 = y1i * MW + x1i;

    const int plane = MH * MW;
    float res[3];
#pragma unroll
    for (int c = 0; c < NCH; ++c) {
        const float* p0 = mips + (i0 * NCH + c) * plane;
        const float* p1 = mips + (i1 * NCH + c) * plane;
        float c0 = p0[o00] * w00 + p0[o01] * w01 + p0[o10] * w10 + p0[o11] * w11;
        float c1 = p1[o00] * w00 + p1[o01] * w01 + p1[o10] * w10 + p1[o11] * w11;
        res[c] = c0 + w * (c1 - c0);
    }

    out[pix * 3 + 0] = res[0];
    out[pix * 3 + 1] = res[1];
    out[pix * 3 + 2] = res[2];
}

extern "C" void kernel_launch(void* const* d_in, const int* in_sizes, int n_in,
                              void* d_out, int out_size, void* d_ws, size_t ws_size,
                              hipStream_t stream) {
    const float* x = (const float*)d_in[0];
    const float* rough = (const float*)d_in[1];
    const float* mips = (const float*)d_in[2];
    float* out = (float*)d_out;

    int threads = 256;
    int blocks = (NPIX + threads - 1) / threads;
    envlight_kernel<<<blocks, threads, 0, stream>>>(x, rough, mips, out);
}

// Round 2
// 43.748 us; speedup vs baseline: 2.4108x; 2.4108x over previous
//
#include <hip/hip_runtime.h>

#define IMG_H 1080
#define IMG_W 1920
#define NPIX (IMG_H * IMG_W)
#define NMIP 8
#define NCH 3
#define MH 128
#define MW 256
#define MIN_R 0.08f
#define MAX_R 0.5f

typedef _Float16 half_t;
typedef __attribute__((ext_vector_type(8))) _Float16 half8;    // 16 B
typedef __attribute__((ext_vector_type(8))) unsigned short ushort8;

// Workspace texture layout: (MH, MW, NMIP, 4) fp16.
// One texel record = 8 mips * 4 ch * 2B = 64 B, 64B-aligned.
#define REC_HALFS 32
#define TEX_BYTES (MH * MW * REC_HALFS * 2)   // 2 MiB

// ---------------- repack: (8,3,128,256) f32 -> (128,256,8,4) f16 ----------------
__global__ __launch_bounds__(256) void repack_kernel(
    const float* __restrict__ mips, half_t* __restrict__ tex)
{
    int t = blockIdx.x * blockDim.x + threadIdx.x;   // texel id
    if (t >= MH * MW) return;
    int y = t >> 8;          // t / MW
    int x = t & (MW - 1);    // t % MW

    half8 v[4];
#pragma unroll
    for (int m = 0; m < NMIP; ++m) {
#pragma unroll
        for (int c = 0; c < 4; ++c) {
            float f = (c < NCH) ? mips[((m * NCH + c) * MH + y) * MW + x] : 0.0f;
            v[m >> 1][(m & 1) * 4 + c] = (half_t)f;
        }
    }
    half8* dst = (half8*)(tex + (size_t)t * REC_HALFS);
    dst[0] = v[0]; dst[1] = v[1]; dst[2] = v[2]; dst[3] = v[3];
}

// ---------------- main: one thread per pixel, 4 scattered 16B loads ----------------
__global__ __launch_bounds__(256) void envlight_main(
    const float* __restrict__ x,      // (H,W,3)
    const float* __restrict__ rough,  // (H,W,1)
    const half_t* __restrict__ tex,   // (128,256,8,4) f16
    float* __restrict__ out)          // (H,W,3)
{
    int pix = blockIdx.x * blockDim.x + threadIdx.x;
    if (pix >= NPIX) return;

    float dx = x[pix * 3 + 0];
    float dy = x[pix * 3 + 1];
    float dz = x[pix * 3 + 2];

    const float INV_PI = 0.31830988618379067f;
    float theta = acosf(fminf(fmaxf(dz, -1.0f), 1.0f));
    float phi = atan2f(dy, dx);
    float gx = phi * INV_PI;                  // 2u-1
    float gy = 2.0f * theta * INV_PI - 1.0f;  // 2v-1

    float ixf = ((gx + 1.0f) * (float)MW - 1.0f) * 0.5f;
    float iyf = ((gy + 1.0f) * (float)MH - 1.0f) * 0.5f;
    float x0f = floorf(ixf);
    float y0f = floorf(iyf);
    float wx = ixf - x0f;
    float wy = iyf - y0f;
    int x0 = (int)x0f;
    int y0 = (int)y0f;
    int x0i = min(max(x0, 0), MW - 1);
    int x1i = min(max(x0 + 1, 0), MW - 1);
    int y0i = min(max(y0, 0), MH - 1);
    int y1i = min(max(y0 + 1, 0), MH - 1);

    // roughness -> fractional mip
    float r = fminf(fmaxf(rough[pix], MIN_R), MAX_R);
    float idx = (r - MIN_R) * ((float)(NMIP - 1) / (MAX_R - MIN_R));
    float idxf = floorf(idx);
    int i0 = min((int)idxf, NMIP - 2);   // idx >= 0 always
    float w = idx - idxf;                // w==0 cases make implicit i1=i0+1 exact

    float w00 = (1.0f - wx) * (1.0f - wy);
    float w01 = wx * (1.0f - wy);
    float w10 = (1.0f - wx) * wy;
    float w11 = wx * wy;

    int t00 = y0i * MW + x0i;
    int t01 = y0i * MW + x1i;
    int t10 = y1i * MW + x0i;
    int t11 = y1i * MW + x1i;

    float a0 = 0.f, a1 = 0.f, a2 = 0.f;   // bilinear accum, mip i0
    float b0 = 0.f, b1 = 0.f, b2 = 0.f;   // bilinear accum, mip i0+1
    const int ts[4] = {t00, t01, t10, t11};
    const float wb[4] = {w00, w01, w10, w11};
#pragma unroll
    for (int k = 0; k < 4; ++k) {
        // 16B load at byte offset t*64 + i0*8: always within one 64B record
        half8 raw = *(const half8*)(tex + (size_t)ts[k] * REC_HALFS + i0 * 4);
        float wk = wb[k];
        a0 += wk * (float)raw[0];
        a1 += wk * (float)raw[1];
        a2 += wk * (float)raw[2];
        b0 += wk * (float)raw[4];
        b1 += wk * (float)raw[5];
        b2 += wk * (float)raw[6];
    }

    out[pix * 3 + 0] = a0 + w * (b0 - a0);
    out[pix * 3 + 1] = a1 + w * (b1 - a1);
    out[pix * 3 + 2] = a2 + w * (b2 - a2);
}

// ---------------- fallback (round-1 direct kernel) if ws too small ----------------
__global__ __launch_bounds__(256) void envlight_direct(
    const float* __restrict__ x, const float* __restrict__ rough,
    const float* __restrict__ mips, float* __restrict__ out)
{
    int pix = blockIdx.x * blockDim.x + threadIdx.x;
    if (pix >= NPIX) return;

    float dx = x[pix * 3 + 0], dy = x[pix * 3 + 1], dz = x[pix * 3 + 2];
    const float INV_PI = 0.31830988618379067f;
    float theta = acosf(fminf(fmaxf(dz, -1.0f), 1.0f));
    float phi = atan2f(dy, dx);
    float gx = phi * INV_PI;
    float gy = 2.0f * theta * INV_PI - 1.0f;

    float ixf = ((gx + 1.0f) * (float)MW - 1.0f) * 0.5f;
    float iyf = ((gy + 1.0f) * (float)MH - 1.0f) * 0.5f;
    float x0f = floorf(ixf), y0f = floorf(iyf);
    float wx = ixf - x0f, wy = iyf - y0f;
    int x0 = (int)x0f, y0 = (int)y0f;
    int x0i = min(max(x0, 0), MW - 1);
    int x1i = min(max(x0 + 1, 0), MW - 1);
    int y0i = min(max(y0, 0), MH - 1);
    int y1i = min(max(y0 + 1, 0), MH - 1);

    float r = fminf(fmaxf(rough[pix], MIN_R), MAX_R);
    float idx = (r - MIN_R) * ((float)(NMIP - 1) / (MAX_R - MIN_R));
    float idxf = floorf(idx);
    int i0 = min((int)idxf, NMIP - 2);
    int i1 = min(max((int)ceilf(idx), 0), NMIP - 1);
    float w = idx - idxf;

    float w00 = (1.0f - wx) * (1.0f - wy);
    float w01 = wx * (1.0f - wy);
    float w10 = (1.0f - wx) * wy;
    float w11 = wx * wy;
    int o00 = y0i * MW + x0i, o01 = y0i * MW + x1i;
    int o10 = y1i * MW + x0i, o11 = y1i * MW + x1i;

    const int plane = MH * MW;
#pragma unroll
    for (int c = 0; c < NCH; ++c) {
        const float* p0 = mips + (i0 * NCH + c) * plane;
        const float* p1 = mips + (i1 * NCH + c) * plane;
        float c0 = p0[o00] * w00 + p0[o01] * w01 + p0[o10] * w10 + p0[o11] * w11;
        float c1 = p1[o00] * w00 + p1[o01] * w01 + p1[o10] * w10 + p1[o11] * w11;
        out[pix * 3 + c] = c0 + w * (c1 - c0);
    }
}

extern "C" void kernel_launch(void* const* d_in, const int* in_sizes, int n_in,
                              void* d_out, int out_size, void* d_ws, size_t ws_size,
                              hipStream_t stream) {
    const float* x = (const float*)d_in[0];
    const float* rough = (const float*)d_in[1];
    const float* mips = (const float*)d_in[2];
    float* out = (float*)d_out;

    int threads = 256;
    int blocks = (NPIX + threads - 1) / threads;

    if (ws_size >= (size_t)TEX_BYTES) {
        half_t* tex = (half_t*)d_ws;
        repack_kernel<<<(MH * MW + threads - 1) / threads, threads, 0, stream>>>(mips, tex);
        envlight_main<<<blocks, threads, 0, stream>>>(x, rough, tex, out);
    } else {
        envlight_direct<<<blocks, threads, 0, stream>>>(x, rough, mips, out);
    }
}